// Round 2
// baseline (1138.021 us; speedup 1.0000x reference)
//
#include <hip/hip_runtime.h>
#include <hip/hip_bf16.h>
#include <math.h>

#define HH 256
#define WW 256
#define CIN 16
#define CHID 32
#define CST 48         // CIN + CHID
#define TS 16          // output tile
#define ST 20          // staged tile (TS + 4): out halo(1) + reset halo(1)
#define RT 18          // reset tile (TS + 2)
#define HWPIX (HH * WW)

typedef unsigned short u16;

__device__ __forceinline__ float b2f(u16 h) {
    union { unsigned int u; float f; } v; v.u = ((unsigned int)h) << 16; return v.f;
}
__device__ __forceinline__ u16 f2b(float f) {
    union { float f; unsigned int u; } v; v.f = f;
    unsigned int r = v.u + 0x7fffu + ((v.u >> 16) & 1u);   // round-nearest-even
    return (u16)(r >> 16);
}

// OIHW [32][48][3][3] -> [48*9][32]  (ci*9+k major, co contiguous)
__global__ void wtrans_kernel(const float* __restrict__ w, float* __restrict__ wt) {
    int i = blockIdx.x * 256 + threadIdx.x;
    if (i < CHID * CST * 9) {
        int co = i / (CST * 9);
        int rem = i - co * (CST * 9);
        wt[rem * CHID + co] = w[i];
    }
}

// One fused kernel: stage masked [x, prev] (bf16, 20x20 halo), compute reset
// conv at 18x18 (halo) -> prev*reset in LDS, then update conv + out conv +
// GRU combine per center pixel. d_out written once, never read. d_ws holds
// only transposed weights (165 KB).
__global__ __launch_bounds__(256, 2) void convgru_fused(
    const float* __restrict__ x, const float* __restrict__ prev,
    const int* __restrict__ mask,
    const float* __restrict__ wtR, const float* __restrict__ bR,
    const float* __restrict__ wtU, const float* __restrict__ bU,
    const float* __restrict__ wtO, const float* __restrict__ bO,
    float* __restrict__ out)
{
    __shared__ u16  s1[CST * ST * ST];    // masked stacked input, 38400 B
    __shared__ u16  rr[CHID * RT * RT];   // prev*reset (masked), 20736 B
    __shared__ float smask[ST * ST];      // mask tile, 1600 B

    const int b   = blockIdx.z;
    const int y0  = blockIdx.y * TS, x0 = blockIdx.x * TS;
    const int tid = threadIdx.x;

    // --- stage mask tile ---
    for (int p = tid; p < ST * ST; p += 256) {
        int yy = p / ST, xx = p - yy * ST;
        int gy = y0 + yy - 2, gx = x0 + xx - 2;
        float m = 0.f;
        if ((unsigned)gy < HH && (unsigned)gx < WW)
            m = (float)mask[(b * HH + gy) * WW + gx];
        smask[p] = m;
    }
    __syncthreads();

    // --- stage masked stacked inputs (bf16) ---
    for (int l = tid; l < CST * ST * ST; l += 256) {
        int ci = l / (ST * ST);
        int p  = l - ci * (ST * ST);
        int yy = p / ST, xx = p - yy * ST;
        int gy = y0 + yy - 2, gx = x0 + xx - 2;
        float v = 0.f;
        if ((unsigned)gy < HH && (unsigned)gx < WW) {
            float t = (ci < CIN) ? x[(b * CIN + ci) * HWPIX + gy * WW + gx]
                                 : prev[(b * CHID + ci - CIN) * HWPIX + gy * WW + gx];
            v = t * smask[p];
        }
        s1[l] = f2b(v);
    }
    __syncthreads();

    // --- Phase R: reset conv at 18x18, rr = staged_prev * sigmoid(conv+bR) ---
    for (int rnd = 0; rnd < 2; rnd++) {
        int pos = rnd * 256 + tid;
        if (pos < RT * RT) {
            int pry = pos / RT, prx = pos - pry * RT;
            float acc[CHID];
            #pragma unroll
            for (int c = 0; c < CHID; c++) acc[c] = 0.f;
            for (int ci = 0; ci < CST; ci++) {
                const u16* sp = &s1[ci * (ST * ST) + pry * ST + prx];
                #pragma unroll
                for (int k = 0; k < 9; k++) {
                    int ky = k / 3, kx = k - ky * 3;
                    float v = b2f(sp[ky * ST + kx]);
                    const float* wr = &wtR[(ci * 9 + k) * CHID];
                    #pragma unroll
                    for (int c = 0; c < CHID; c++) acc[c] = fmaf(v, wr[c], acc[c]);
                }
            }
            #pragma unroll
            for (int c = 0; c < CHID; c++) {
                float z = acc[c] + bR[c];
                z = fminf(fmaxf(z, -30.f), 30.f);
                float sg = 1.f / (1.f + __expf(-z));
                // staged prev already carries mask; sites outside image are 0
                float pm = b2f(s1[(CIN + c) * (ST * ST) + (pry + 1) * ST + prx + 1]);
                rr[c * (RT * RT) + pos] = f2b(pm * sg);
            }
        }
    }
    __syncthreads();

    const int py = tid >> 4, px = tid & 15;
    const int yc = y0 + py, xc = x0 + px;
    const float m = smask[(py + 2) * ST + (px + 2)];

    // --- Phase U: update conv at center pixel -> u[c] in registers ---
    float u[CHID];
    {
        float acc[CHID];
        #pragma unroll
        for (int c = 0; c < CHID; c++) acc[c] = 0.f;
        for (int ci = 0; ci < CST; ci++) {
            const u16* sp = &s1[ci * (ST * ST) + (py + 1) * ST + (px + 1)];
            #pragma unroll
            for (int k = 0; k < 9; k++) {
                int ky = k / 3, kx = k - ky * 3;
                float v = b2f(sp[ky * ST + kx]);
                const float* wu = &wtU[(ci * 9 + k) * CHID];
                #pragma unroll
                for (int c = 0; c < CHID; c++) acc[c] = fmaf(v, wu[c], acc[c]);
            }
        }
        #pragma unroll
        for (int c = 0; c < CHID; c++) {
            float z = acc[c] + bU[c];
            z = fminf(fmaxf(z, -30.f), 30.f);
            u[c] = m / (1.f + __expf(-z));
        }
    }

    // --- Phase O: out conv over [x part of s1, rr], tanh, GRU combine ---
    {
        float acc[CHID];
        #pragma unroll
        for (int c = 0; c < CHID; c++) acc[c] = 0.f;
        for (int ci = 0; ci < CIN; ci++) {
            const u16* sp = &s1[ci * (ST * ST) + (py + 1) * ST + (px + 1)];
            #pragma unroll
            for (int k = 0; k < 9; k++) {
                int ky = k / 3, kx = k - ky * 3;
                float v = b2f(sp[ky * ST + kx]);
                const float* wo = &wtO[(ci * 9 + k) * CHID];
                #pragma unroll
                for (int c = 0; c < CHID; c++) acc[c] = fmaf(v, wo[c], acc[c]);
            }
        }
        for (int ci = 0; ci < CHID; ci++) {
            const u16* rp = &rr[ci * (RT * RT) + py * RT + px];
            #pragma unroll
            for (int k = 0; k < 9; k++) {
                int ky = k / 3, kx = k - ky * 3;
                float v = b2f(rp[ky * RT + kx]);
                const float* wo = &wtO[((CIN + ci) * 9 + k) * CHID];
                #pragma unroll
                for (int c = 0; c < CHID; c++) acc[c] = fmaf(v, wo[c], acc[c]);
            }
        }
        #pragma unroll
        for (int c = 0; c < CHID; c++) {
            float z = acc[c] + bO[c];
            z = fminf(fmaxf(z, -20.f), 20.f);
            float e2 = __expf(2.f * z);
            float t = (1.f - 2.f / (e2 + 1.f)) * m;       // tanh(z)*m
            int oidx = ((b * CHID + c) * HH + yc) * WW + xc;
            float pm = prev[oidx] * m;
            out[oidx] = pm * (1.f - u[c]) + t * u[c];
        }
    }
}

extern "C" void kernel_launch(void* const* d_in, const int* in_sizes, int n_in,
                              void* d_out, int out_size, void* d_ws, size_t ws_size,
                              hipStream_t stream) {
    const float* x       = (const float*)d_in[0];
    const float* prev    = (const float*)d_in[1];
    const int*   mask    = (const int*)d_in[2];
    const float* w_reset = (const float*)d_in[3];
    const float* b_reset = (const float*)d_in[4];
    const float* w_upd   = (const float*)d_in[5];
    const float* b_upd   = (const float*)d_in[6];
    const float* w_out   = (const float*)d_in[7];
    const float* b_out   = (const float*)d_in[8];
    float* out = (float*)d_out;

    const int wN = CHID * CST * 9;     // 13824 floats per set
    float* wtR = (float*)d_ws;
    float* wtU = wtR + wN;
    float* wtO = wtU + wN;

    dim3 wg((wN + 255) / 256);
    wtrans_kernel<<<wg, 256, 0, stream>>>(w_reset, wtR);
    wtrans_kernel<<<wg, 256, 0, stream>>>(w_upd,   wtU);
    wtrans_kernel<<<wg, 256, 0, stream>>>(w_out,   wtO);

    dim3 grid(WW / TS, HH / TS, 8);
    convgru_fused<<<grid, 256, 0, stream>>>(x, prev, mask,
                                            wtR, b_reset, wtU, b_upd,
                                            wtO, b_out, out);
}

// Round 4
// 214.618 us; speedup vs baseline: 5.3025x; 5.3025x over previous
//
#include <hip/hip_runtime.h>
#include <hip/hip_bf16.h>
#include <math.h>

#define HH 256
#define WW 256
#define CIN 16
#define CHID 32
#define CST 48
#define TS 16
#define HWPIX (HH * WW)

#define SP 56                   // s1 pixel stride (elems) -> 112 B, 16B-aligned
#define S1_ELEMS (400 * SP)     // 22400
#define RP 40                   // rr pixel stride (elems) -> 80 B, 16B-aligned
#define RR_BASE S1_ELEMS
#define RR_ELEMS (324 * RP)     // 12960
#define NKS 14                  // ceil(432/32) K-steps (pad to 448 with zero-B)

typedef unsigned short u16;
typedef __attribute__((ext_vector_type(8))) short short8;
typedef __attribute__((ext_vector_type(8))) __bf16 bf16x8;
typedef __attribute__((ext_vector_type(4))) float f32x4;

__device__ __forceinline__ float b2f(u16 h) {
    union { unsigned u; float f; } v; v.u = ((unsigned)h) << 16; return v.f;
}
__device__ __forceinline__ u16 f2b(float f) {
    union { float f; unsigned u; } v; v.f = f;
    unsigned r = v.u + 0x7fffu + ((v.u >> 16) & 1u);
    return (u16)(r >> 16);
}
__device__ __forceinline__ int imin(int a, int b) { return a < b ? a : b; }

// Pre-gather MFMA B fragments per lane: pB[conv][ks][nf][lane][j], 3*14*2*64*8 bf16
__global__ void packb_kernel(const float* __restrict__ wR, const float* __restrict__ wU,
                             const float* __restrict__ wO, u16* __restrict__ pB) {
    int i = blockIdx.x * 256 + threadIdx.x;
    const int TOT = 3 * NKS * 2 * 64 * 8;
    if (i >= TOT) return;
    int conv = i / (NKS * 2 * 64 * 8);
    int r = i - conv * (NKS * 2 * 64 * 8);
    int ks = r / (2 * 64 * 8); r -= ks * (2 * 64 * 8);
    int nf = r / (64 * 8);     r -= nf * (64 * 8);
    int lane = r >> 3, j = r & 7;
    int k = ks * 32 + (lane >> 4) * 8 + j;
    int n = nf * 16 + (lane & 15);
    float val = 0.f;
    if (k < 432) {
        int tap = k / 48, ci = k - tap * 48;
        const float* w = (conv == 0) ? wR : (conv == 1) ? wU : wO;
        val = w[(n * CST + ci) * 9 + tap];   // OIHW, tap = ky*3+kx
    }
    pB[i] = f2b(val);
}

__global__ __launch_bounds__(256, 2) void convgru_mfma(
    const float* __restrict__ x, const float* __restrict__ prev,
    const int* __restrict__ mask, const u16* __restrict__ pB,
    const float* __restrict__ bR, const float* __restrict__ bU,
    const float* __restrict__ bO, float* __restrict__ out)
{
    __shared__ u16 smemS[S1_ELEMS + RR_ELEMS];   // 70720 B
    __shared__ float smask[400];

    const int b   = blockIdx.z;
    const int y0  = blockIdx.y * TS, x0 = blockIdx.x * TS;
    const int tid = threadIdx.x;
    const int w   = tid >> 6;        // wave id 0..3
    const int lane = tid & 63;
    const int run  = lane >> 4;      // k-run group
    const int lo   = lane & 15;      // M-column / N-col within fragment

    // ---- stage mask tile (20x20, offset -2) ----
    for (int p = tid; p < 400; p += 256) {
        int yy = (p * 205) >> 12, xx = p - yy * 20;
        int gy = y0 + yy - 2, gx = x0 + xx - 2;
        float mv = 0.f;
        if ((unsigned)gy < HH && (unsigned)gx < WW)
            mv = (float)mask[(b * HH + gy) * WW + gx];
        smask[p] = mv;
    }
    __syncthreads();

    // ---- stage masked [x, prev] channel-last bf16: s1[pix][ci], pix stride SP ----
    for (int l = tid; l < 19200; l += 256) {
        int ci = (l * 5243) >> 21;           // /400
        int p  = l - ci * 400;
        int yy = (p * 205) >> 12, xx = p - yy * 20;   // /20
        int gy = y0 + yy - 2, gx = x0 + xx - 2;
        float v = 0.f;
        if ((unsigned)gy < HH && (unsigned)gx < WW) {
            float t = (ci < CIN) ? x[(b * CIN + ci) * HWPIX + gy * WW + gx]
                                 : prev[(b * CHID + ci - CIN) * HWPIX + gy * WW + gx];
            v = t * smask[p];
        }
        smemS[p * SP + ci] = f2b(v);
    }
    __syncthreads();

    const short8* pB8 = (const short8*)pB;
    const f32x4 z4 = {0.f, 0.f, 0.f, 0.f};

    // ================= Phase R: reset conv on 18x18 halo grid =================
    // M = 324 linear pixels (18x18), fragments of 16: frag = w + f*4, f=0..5
    f32x4 accR[6][2];
    #pragma unroll
    for (int f = 0; f < 6; f++) { accR[f][0] = z4; accR[f][1] = z4; }

    int pbase[6];
    #pragma unroll
    for (int f = 0; f < 6; f++) {
        int frag = w + f * 4;
        int idx = imin(frag * 16 + lo, 323);
        int ry = (idx * 57) >> 10;           // /18
        int rx = idx - ry * 18;
        pbase[f] = (ry * 20 + rx) * SP;
    }

    #pragma unroll
    for (int ks = 0; ks < NKS; ks++) {
        int k = ks * 32 + run * 8;
        int tap = imin((k * 1366) >> 16, 8); // /48, clamp pad region
        int ci  = imin(k - tap * 48, 40);
        int ky = (tap * 11) >> 5;            // /3
        int kx = tap - ky * 3;
        int partk = (ky * 20 + kx) * SP + ci;
        short8 b0 = pB8[(0 * NKS + ks) * 128 + lane];
        short8 b1 = pB8[(0 * NKS + ks) * 128 + 64 + lane];
        #pragma unroll
        for (int f = 0; f < 6; f++) {
            if (f == 5 && w > 0) continue;   // frags 0..20 only
            short8 av = *(const short8*)&smemS[pbase[f] + partk];
            bf16x8 a = __builtin_bit_cast(bf16x8, av);
            accR[f][0] = __builtin_amdgcn_mfma_f32_16x16x32_bf16(a, __builtin_bit_cast(bf16x8, b0), accR[f][0], 0, 0, 0);
            accR[f][1] = __builtin_amdgcn_mfma_f32_16x16x32_bf16(a, __builtin_bit_cast(bf16x8, b1), accR[f][1], 0, 0, 0);
        }
    }

    // R epilogue: rr[pix][c] = staged_prev * sigmoid(acc + bR)
    {
        float bRv0 = bR[lo], bRv1 = bR[16 + lo];
        #pragma unroll
        for (int f = 0; f < 6; f++) {
            if (f == 5 && w > 0) continue;
            int frag = w + f * 4;
            #pragma unroll
            for (int nf = 0; nf < 2; nf++) {
                int c = nf * 16 + lo;
                float bb = nf ? bRv1 : bRv0;
                #pragma unroll
                for (int reg = 0; reg < 4; reg++) {
                    int idx = frag * 16 + run * 4 + reg;   // m = run*4+reg
                    bool valid = idx < 324;
                    int idc = imin(idx, 323);
                    int ry = (idc * 57) >> 10, rx = idc - ry * 18;
                    float z = accR[f][nf][reg] + bb;
                    z = fminf(fmaxf(z, -30.f), 30.f);
                    float sg = 1.f / (1.f + __expf(-z));
                    float pm = b2f(smemS[((ry + 1) * 20 + rx + 1) * SP + CIN + c]);
                    if (valid) smemS[RR_BASE + idx * RP + c] = f2b(pm * sg);
                }
            }
        }
    }

    // ================= Phase U: update conv at 16x16 centers =================
    // Fragment (w,f): pixel row py = w + f*4, columns 0..15 (M index = column = lo)
    f32x4 accU[4][2];
    #pragma unroll
    for (int f = 0; f < 4; f++) { accU[f][0] = z4; accU[f][1] = z4; }

    #pragma unroll
    for (int ks = 0; ks < NKS; ks++) {
        int k = ks * 32 + run * 8;
        int tap = imin((k * 1366) >> 16, 8);
        int ci  = imin(k - tap * 48, 40);
        int ky = (tap * 11) >> 5, kx = tap - ky * 3;
        // staged addr: row = py + ky + 1 (py = w + 4f), col = lo + kx + 1
        int aoff = ((ky + 1 + w) * 20 + kx + 1 + lo) * SP + ci;
        short8 b0 = pB8[(1 * NKS + ks) * 128 + lane];
        short8 b1 = pB8[(1 * NKS + ks) * 128 + 64 + lane];
        #pragma unroll
        for (int f = 0; f < 4; f++) {
            short8 av = *(const short8*)&smemS[aoff + f * (4 * 20 * SP)];
            bf16x8 a = __builtin_bit_cast(bf16x8, av);
            accU[f][0] = __builtin_amdgcn_mfma_f32_16x16x32_bf16(a, __builtin_bit_cast(bf16x8, b0), accU[f][0], 0, 0, 0);
            accU[f][1] = __builtin_amdgcn_mfma_f32_16x16x32_bf16(a, __builtin_bit_cast(bf16x8, b1), accU[f][1], 0, 0, 0);
        }
    }

    __syncthreads();   // rr writes visible before O-phase gathers

    // ===== Phase O: out conv over [x(ci<16) from s1, prev*reset from rr] =====
    f32x4 accO[4][2];
    #pragma unroll
    for (int f = 0; f < 4; f++) { accO[f][0] = z4; accO[f][1] = z4; }

    #pragma unroll
    for (int ks = 0; ks < NKS; ks++) {
        int k = ks * 32 + run * 8;
        int tap = imin((k * 1366) >> 16, 8);
        int ci  = imin(k - tap * 48, 40);
        int ky = (tap * 11) >> 5, kx = tap - ky * 3;
        bool isx = ci < CIN;
        // s1: row = py + ky + 1, col = lo + kx + 1 ; rr: row = py + ky, col = lo + kx
        int offx = ((ky + 1 + w) * 20 + kx + 1 + lo) * SP + ci;
        int offr = RR_BASE + ((ky + w) * 18 + kx + lo) * RP + (ci - CIN);
        int step = isx ? (20 * SP) : (18 * RP);
        int ab = isx ? offx : offr;
        int fstep = 4 * step;
        short8 b0 = pB8[(2 * NKS + ks) * 128 + lane];
        short8 b1 = pB8[(2 * NKS + ks) * 128 + 64 + lane];
        #pragma unroll
        for (int f = 0; f < 4; f++) {
            short8 av = *(const short8*)&smemS[ab];
            bf16x8 a = __builtin_bit_cast(bf16x8, av);
            accO[f][0] = __builtin_amdgcn_mfma_f32_16x16x32_bf16(a, __builtin_bit_cast(bf16x8, b0), accO[f][0], 0, 0, 0);
            accO[f][1] = __builtin_amdgcn_mfma_f32_16x16x32_bf16(a, __builtin_bit_cast(bf16x8, b1), accO[f][1], 0, 0, 0);
            ab += fstep;
        }
    }

    // ================= Final epilogue: GRU combine, one store per value ======
    {
        float bUv0 = bU[lo], bUv1 = bU[16 + lo];
        float bOv0 = bO[lo], bOv1 = bO[16 + lo];
        #pragma unroll
        for (int f = 0; f < 4; f++) {
            int py = w + f * 4;
            #pragma unroll
            for (int nf = 0; nf < 2; nf++) {
                int c = nf * 16 + lo;
                float bu = nf ? bUv1 : bUv0;
                float bo = nf ? bOv1 : bOv0;
                #pragma unroll
                for (int reg = 0; reg < 4; reg++) {
                    int px = run * 4 + reg;                 // m = run*4+reg
                    float mm = smask[(py + 2) * 20 + px + 2];
                    float zu = accU[f][nf][reg] + bu;
                    zu = fminf(fmaxf(zu, -30.f), 30.f);
                    float uu = mm / (1.f + __expf(-zu));
                    float zo = accO[f][nf][reg] + bo;
                    zo = fminf(fmaxf(zo, -20.f), 20.f);
                    float e2 = __expf(2.f * zo);
                    float t = (1.f - 2.f / (e2 + 1.f)) * mm;   // tanh*m
                    float pm = b2f(smemS[((py + 2) * 20 + px + 2) * SP + CIN + c]); // prev*m
                    int gi = ((b * CHID + c) * HH + y0 + py) * WW + x0 + px;
                    out[gi] = pm * (1.f - uu) + t * uu;
                }
            }
        }
    }
}

extern "C" void kernel_launch(void* const* d_in, const int* in_sizes, int n_in,
                              void* d_out, int out_size, void* d_ws, size_t ws_size,
                              hipStream_t stream) {
    const float* x       = (const float*)d_in[0];
    const float* prev    = (const float*)d_in[1];
    const int*   mask    = (const int*)d_in[2];
    const float* w_reset = (const float*)d_in[3];
    const float* b_reset = (const float*)d_in[4];
    const float* w_upd   = (const float*)d_in[5];
    const float* b_upd   = (const float*)d_in[6];
    const float* w_out   = (const float*)d_in[7];
    const float* b_out   = (const float*)d_in[8];
    float* out = (float*)d_out;

    u16* pB = (u16*)d_ws;                        // 3*14*2*64*8 = 43008 bf16 = 86 KB
    const int TOT = 3 * NKS * 2 * 64 * 8;
    packb_kernel<<<(TOT + 255) / 256, 256, 0, stream>>>(w_reset, w_upd, w_out, pB);

    dim3 grid(WW / TS, HH / TS, 8);
    convgru_mfma<<<grid, 256, 0, stream>>>(x, prev, mask, pB,
                                           b_reset, b_upd, b_out, out);
}

// Round 5
// 144.476 us; speedup vs baseline: 7.8769x; 1.4855x over previous
//
#include <hip/hip_runtime.h>
#include <hip/hip_bf16.h>
#include <math.h>

#define HH 256
#define WW 256
#define CIN 16
#define CHID 32
#define CST 48
#define TS 16
#define HWPIX (HH * WW)

#define SP 48                   // s1 pixel stride (elems) -> 96 B, 16B-aligned
#define NKS 14                  // ceil(432/32) K-steps (pad to 448 with zero-B)

typedef unsigned short u16;
typedef __attribute__((ext_vector_type(8))) short short8;
typedef __attribute__((ext_vector_type(8))) __bf16 bf16x8;
typedef __attribute__((ext_vector_type(4))) float f32x4;

__device__ __forceinline__ float b2f(u16 h) {
    union { unsigned u; float f; } v; v.u = ((unsigned)h) << 16; return v.f;
}
__device__ __forceinline__ u16 f2b(float f) {
    union { float f; unsigned u; } v; v.f = f;
    unsigned r = v.u + 0x7fffu + ((v.u >> 16) & 1u);
    return (u16)(r >> 16);
}
__device__ __forceinline__ int imin(int a, int b) { return a < b ? a : b; }

// Pre-gather MFMA B fragments per lane: pB[conv][ks][nf][lane][j], 3*14*2*64*8 bf16
__global__ void packb_kernel(const float* __restrict__ wR, const float* __restrict__ wU,
                             const float* __restrict__ wO, u16* __restrict__ pB) {
    int i = blockIdx.x * 256 + threadIdx.x;
    const int TOT = 3 * NKS * 2 * 64 * 8;
    if (i >= TOT) return;
    int conv = i / (NKS * 2 * 64 * 8);
    int r = i - conv * (NKS * 2 * 64 * 8);
    int ks = r / (2 * 64 * 8); r -= ks * (2 * 64 * 8);
    int nf = r / (64 * 8);     r -= nf * (64 * 8);
    int lane = r >> 3, j = r & 7;
    int k = ks * 32 + (lane >> 4) * 8 + j;
    int n = nf * 16 + (lane & 15);
    float val = 0.f;
    if (k < 432) {
        int tap = k / 48, ci = k - tap * 48;
        const float* w = (conv == 0) ? wR : (conv == 1) ? wU : wO;
        val = w[(n * CST + ci) * 9 + tap];   // OIHW, tap = ky*3+kx
    }
    pB[i] = f2b(val);
}

// Fused ConvGRU. LDS: s1 = 20x20 halo tile, channel-last [48], pixel stride 48
// (38.4 KB) + mask (1.6 KB) = 40.0 KB -> 4 blocks/CU.
// Order: stage -> U-MFMA + R-MFMA (read original prev) -> pm-save to regs ->
// barrier -> R-epilogue writes prev*reset IN PLACE over s1 prev channels ->
// barrier -> O-MFMA (uniform [x, prev*reset] addressing) -> GRU combine.
__global__ __launch_bounds__(256, 4) void convgru_mfma(
    const float* __restrict__ x, const float* __restrict__ prev,
    const int* __restrict__ mask, const u16* __restrict__ pB,
    const float* __restrict__ bR, const float* __restrict__ bU,
    const float* __restrict__ bO, float* __restrict__ out)
{
    __shared__ u16 s1[400 * SP];     // 38400 B
    __shared__ float smask[400];     // 1600 B

    const int b   = blockIdx.z;
    const int y0  = blockIdx.y * TS, x0 = blockIdx.x * TS;
    const int tid = threadIdx.x;
    const int w   = tid >> 6;        // wave id 0..3
    const int lane = tid & 63;
    const int run  = lane >> 4;      // k-run / D-row group
    const int lo   = lane & 15;      // A-row (pixel col) / D-col (channel)

    // ---- stage mask tile (20x20, offset -2) ----
    for (int p = tid; p < 400; p += 256) {
        int yy = (p * 205) >> 12, xx = p - yy * 20;
        int gy = y0 + yy - 2, gx = x0 + xx - 2;
        float mv = 0.f;
        if ((unsigned)gy < HH && (unsigned)gx < WW)
            mv = (float)mask[(b * HH + gy) * WW + gx];
        smask[p] = mv;
    }
    __syncthreads();

    // ---- stage masked [x, prev] channel-last bf16: s1[pix][ci] ----
    for (int l = tid; l < 19200; l += 256) {
        int ci = (l * 5243) >> 21;           // /400
        int p  = l - ci * 400;
        int yy = (p * 205) >> 12, xx = p - yy * 20;   // /20
        int gy = y0 + yy - 2, gx = x0 + xx - 2;
        float v = 0.f;
        if ((unsigned)gy < HH && (unsigned)gx < WW) {
            float t = (ci < CIN) ? x[(b * CIN + ci) * HWPIX + gy * WW + gx]
                                 : prev[(b * CHID + ci - CIN) * HWPIX + gy * WW + gx];
            v = t * smask[p];
        }
        s1[p * SP + ci] = f2b(v);
    }
    __syncthreads();

    const short8* pB8 = (const short8*)pB;
    const f32x4 z4 = {0.f, 0.f, 0.f, 0.f};

    // ========== Phase U: update conv at 16x16 centers (original prev) ==========
    f32x4 accU[4][2];
    #pragma unroll
    for (int f = 0; f < 4; f++) { accU[f][0] = z4; accU[f][1] = z4; }

    #pragma unroll
    for (int ks = 0; ks < NKS; ks++) {
        int k = ks * 32 + run * 8;
        int tap = imin((k * 1366) >> 16, 8);
        int ci  = imin(k - tap * 48, 40);
        int ky = (tap * 11) >> 5, kx = tap - ky * 3;
        int aoff = ((ky + 1 + w) * 20 + kx + 1 + lo) * SP + ci;
        short8 b0 = pB8[(1 * NKS + ks) * 128 + lane];
        short8 b1 = pB8[(1 * NKS + ks) * 128 + 64 + lane];
        #pragma unroll
        for (int f = 0; f < 4; f++) {
            short8 av = *(const short8*)&s1[aoff + f * (4 * 20 * SP)];
            bf16x8 a = __builtin_bit_cast(bf16x8, av);
            accU[f][0] = __builtin_amdgcn_mfma_f32_16x16x32_bf16(a, __builtin_bit_cast(bf16x8, b0), accU[f][0], 0, 0, 0);
            accU[f][1] = __builtin_amdgcn_mfma_f32_16x16x32_bf16(a, __builtin_bit_cast(bf16x8, b1), accU[f][1], 0, 0, 0);
        }
    }

    // ========== Phase R: reset conv on 18x18 halo grid (original prev) ==========
    f32x4 accR[6][2];
    #pragma unroll
    for (int f = 0; f < 6; f++) { accR[f][0] = z4; accR[f][1] = z4; }

    int pbase[6];
    #pragma unroll
    for (int f = 0; f < 6; f++) {
        int frag = w + f * 4;
        int idx = imin(frag * 16 + lo, 323);
        int ry = (idx * 57) >> 10;           // /18
        int rx = idx - ry * 18;
        pbase[f] = (ry * 20 + rx) * SP;
    }

    #pragma unroll
    for (int ks = 0; ks < NKS; ks++) {
        int k = ks * 32 + run * 8;
        int tap = imin((k * 1366) >> 16, 8);
        int ci  = imin(k - tap * 48, 40);
        int ky = (tap * 11) >> 5, kx = tap - ky * 3;
        int partk = (ky * 20 + kx) * SP + ci;
        short8 b0 = pB8[(0 * NKS + ks) * 128 + lane];
        short8 b1 = pB8[(0 * NKS + ks) * 128 + 64 + lane];
        #pragma unroll
        for (int f = 0; f < 6; f++) {
            if (f == 5 && w > 0) continue;   // frags 0..20 only
            short8 av = *(const short8*)&s1[pbase[f] + partk];
            bf16x8 a = __builtin_bit_cast(bf16x8, av);
            accR[f][0] = __builtin_amdgcn_mfma_f32_16x16x32_bf16(a, __builtin_bit_cast(bf16x8, b0), accR[f][0], 0, 0, 0);
            accR[f][1] = __builtin_amdgcn_mfma_f32_16x16x32_bf16(a, __builtin_bit_cast(bf16x8, b1), accR[f][1], 0, 0, 0);
        }
    }

    // ---- pm-save: each thread keeps its epilogue prev*m values (packed) ----
    unsigned pms[4][4];
    #pragma unroll
    for (int f = 0; f < 4; f++) {
        int py = w + f * 4;
        #pragma unroll
        for (int reg = 0; reg < 4; reg++) {
            int px = run * 4 + reg;
            int base = ((py + 2) * 20 + px + 2) * SP + CIN + lo;
            unsigned a0 = s1[base];
            unsigned a1 = s1[base + 16];
            pms[f][reg] = a0 | (a1 << 16);
        }
    }
    __syncthreads();   // all original-prev reads complete before overwrite

    // ---- R epilogue: s1 prev channels <- staged_prev * sigmoid(accR + bR) ----
    {
        float bRv0 = bR[lo], bRv1 = bR[16 + lo];
        #pragma unroll
        for (int f = 0; f < 6; f++) {
            if (f == 5 && w > 0) continue;
            int frag = w + f * 4;
            #pragma unroll
            for (int nf = 0; nf < 2; nf++) {
                int c = nf * 16 + lo;
                float bb = nf ? bRv1 : bRv0;
                #pragma unroll
                for (int reg = 0; reg < 4; reg++) {
                    int idx = frag * 16 + run * 4 + reg;   // m = run*4+reg
                    bool valid = idx < 324;
                    int idc = imin(idx, 323);
                    int ry = (idc * 57) >> 10, rx = idc - ry * 18;
                    int addr = ((ry + 1) * 20 + rx + 1) * SP + CIN + c;
                    float z = accR[f][nf][reg] + bb;
                    z = fminf(fmaxf(z, -30.f), 30.f);
                    float sg = 1.f / (1.f + __expf(-z));
                    float pm = b2f(s1[addr]);
                    if (valid) s1[addr] = f2b(pm * sg);
                }
            }
        }
    }
    __syncthreads();   // overwrite visible before O-phase

    // ========== Phase O: out conv over [x, prev*reset] — same addressing as U ==========
    f32x4 accO[4][2];
    #pragma unroll
    for (int f = 0; f < 4; f++) { accO[f][0] = z4; accO[f][1] = z4; }

    #pragma unroll
    for (int ks = 0; ks < NKS; ks++) {
        int k = ks * 32 + run * 8;
        int tap = imin((k * 1366) >> 16, 8);
        int ci  = imin(k - tap * 48, 40);
        int ky = (tap * 11) >> 5, kx = tap - ky * 3;
        int aoff = ((ky + 1 + w) * 20 + kx + 1 + lo) * SP + ci;
        short8 b0 = pB8[(2 * NKS + ks) * 128 + lane];
        short8 b1 = pB8[(2 * NKS + ks) * 128 + 64 + lane];
        #pragma unroll
        for (int f = 0; f < 4; f++) {
            short8 av = *(const short8*)&s1[aoff + f * (4 * 20 * SP)];
            bf16x8 a = __builtin_bit_cast(bf16x8, av);
            accO[f][0] = __builtin_amdgcn_mfma_f32_16x16x32_bf16(a, __builtin_bit_cast(bf16x8, b0), accO[f][0], 0, 0, 0);
            accO[f][1] = __builtin_amdgcn_mfma_f32_16x16x32_bf16(a, __builtin_bit_cast(bf16x8, b1), accO[f][1], 0, 0, 0);
        }
    }

    // ========== Final epilogue: GRU combine, one store per value ==========
    {
        float bUv0 = bU[lo], bUv1 = bU[16 + lo];
        float bOv0 = bO[lo], bOv1 = bO[16 + lo];
        #pragma unroll
        for (int f = 0; f < 4; f++) {
            int py = w + f * 4;
            #pragma unroll
            for (int nf = 0; nf < 2; nf++) {
                int c = nf * 16 + lo;
                float bu = nf ? bUv1 : bUv0;
                float bo = nf ? bOv1 : bOv0;
                #pragma unroll
                for (int reg = 0; reg < 4; reg++) {
                    int px = run * 4 + reg;                 // m = run*4+reg
                    float mm = smask[(py + 2) * 20 + px + 2];
                    float zu = accU[f][nf][reg] + bu;
                    zu = fminf(fmaxf(zu, -30.f), 30.f);
                    float uu = mm / (1.f + __expf(-zu));
                    float zo = accO[f][nf][reg] + bo;
                    zo = fminf(fmaxf(zo, -20.f), 20.f);
                    float e2 = __expf(2.f * zo);
                    float t = (1.f - 2.f / (e2 + 1.f)) * mm;   // tanh*m
                    float pm = b2f((u16)((pms[f][reg] >> (nf * 16)) & 0xffffu));
                    int gi = ((b * CHID + c) * HH + y0 + py) * WW + x0 + px;
                    out[gi] = pm * (1.f - uu) + t * uu;
                }
            }
        }
    }
}

extern "C" void kernel_launch(void* const* d_in, const int* in_sizes, int n_in,
                              void* d_out, int out_size, void* d_ws, size_t ws_size,
                              hipStream_t stream) {
    const float* x       = (const float*)d_in[0];
    const float* prev    = (const float*)d_in[1];
    const int*   mask    = (const int*)d_in[2];
    const float* w_reset = (const float*)d_in[3];
    const float* b_reset = (const float*)d_in[4];
    const float* w_upd   = (const float*)d_in[5];
    const float* b_upd   = (const float*)d_in[6];
    const float* w_out   = (const float*)d_in[7];
    const float* b_out   = (const float*)d_in[8];
    float* out = (float*)d_out;

    u16* pB = (u16*)d_ws;                        // 3*14*2*64*8 = 43008 bf16 = 86 KB
    const int TOT = 3 * NKS * 2 * 64 * 8;
    packb_kernel<<<(TOT + 255) / 256, 256, 0, stream>>>(w_reset, w_upd, w_out, pB);

    dim3 grid(WW / TS, HH / TS, 8);
    convgru_mfma<<<grid, 256, 0, stream>>>(x, prev, mask, pB,
                                           b_reset, b_upd, b_out, out);
}

// Round 6
// 138.342 us; speedup vs baseline: 8.2261x; 1.0443x over previous
//
#include <hip/hip_runtime.h>
#include <hip/hip_bf16.h>
#include <math.h>

#define HH 256
#define WW 256
#define CIN 16
#define CHID 32
#define CST 48
#define TS 16
#define HWPIX (HH * WW)

#define SP 48                   // s1 pixel stride (elems) -> 96 B, 16B-aligned
#define NKS 14                  // ceil(432/32) K-steps (pad to 448 with zero-B)

typedef unsigned short u16;
typedef unsigned int u32;
typedef __attribute__((ext_vector_type(8))) short short8;
typedef __attribute__((ext_vector_type(8))) __bf16 bf16x8;
typedef __attribute__((ext_vector_type(4))) float f32x4;
typedef __attribute__((ext_vector_type(4))) unsigned int u32x4;

__device__ __forceinline__ float b2f(u16 h) {
    union { unsigned u; float f; } v; v.u = ((unsigned)h) << 16; return v.f;
}
__device__ __forceinline__ u16 f2b(float f) {
    union { float f; unsigned u; } v; v.f = f;
    unsigned r = v.u + 0x7fffu + ((v.u >> 16) & 1u);
    return (u16)(r >> 16);
}
__device__ __forceinline__ int imin(int a, int b) { return a < b ? a : b; }

// Pre-gather MFMA B fragments per lane: pB[conv][ks][nf][lane][j], 3*14*2*64*8 bf16
__global__ void packb_kernel(const float* __restrict__ wR, const float* __restrict__ wU,
                             const float* __restrict__ wO, u16* __restrict__ pB) {
    int i = blockIdx.x * 256 + threadIdx.x;
    const int TOT = 3 * NKS * 2 * 64 * 8;
    if (i >= TOT) return;
    int conv = i / (NKS * 2 * 64 * 8);
    int r = i - conv * (NKS * 2 * 64 * 8);
    int ks = r / (2 * 64 * 8); r -= ks * (2 * 64 * 8);
    int nf = r / (64 * 8);     r -= nf * (64 * 8);
    int lane = r >> 3, j = r & 7;
    int k = ks * 32 + (lane >> 4) * 8 + j;
    int n = nf * 16 + (lane & 15);
    float val = 0.f;
    if (k < 432) {
        int tap = k / 48, ci = k - tap * 48;
        const float* w = (conv == 0) ? wR : (conv == 1) ? wU : wO;
        val = w[(n * CST + ci) * 9 + tap];   // OIHW, tap = ky*3+kx
    }
    pB[i] = f2b(val);
}

__global__ __launch_bounds__(256, 4) void convgru_mfma(
    const float* __restrict__ x, const float* __restrict__ prev,
    const int* __restrict__ mask, const u16* __restrict__ pB,
    const float* __restrict__ bR, const float* __restrict__ bU,
    const float* __restrict__ bO, float* __restrict__ out)
{
    __shared__ __align__(16) unsigned char smem[400 * SP * 2];   // 38400 B
    __shared__ float smask[400];                                  // 1600 B
    u16* s1 = (u16*)smem;
    float* sEp = (float*)smem;          // reused after O-phase (32*260*4 = 33280 B)

    const int b   = blockIdx.z;
    const int y0  = blockIdx.y * TS, x0 = blockIdx.x * TS;
    const int tid = threadIdx.x;
    const int w   = tid >> 6;        // wave id 0..3
    const int lane = tid & 63;
    const int run  = lane >> 4;      // k-run / D-row group
    const int lo   = lane & 15;      // A-row (pixel col) / D-col (channel)

    // ---- staging: pixel-per-thread, channel-inner, packed b128 LDS writes ----
    #pragma unroll
    for (int rp = 0; rp < 2; rp++) {
        int p = rp * 256 + tid;
        bool act = p < 400;
        int pc = act ? p : 399;
        int yy = (pc * 205) >> 12, xx = pc - yy * 20;
        int gy = y0 + yy - 2, gx = x0 + xx - 2;
        bool in = (unsigned)gy < HH && (unsigned)gx < WW;
        int gyc = in ? gy : 0, gxc = in ? gx : 0;
        float mv = in ? (float)mask[(b * HH + gyc) * WW + gxc] : 0.f;
        if (act) {
            smask[pc] = mv;
            const float* xb = x    + (size_t)b * CIN  * HWPIX + gyc * WW + gxc;
            const float* pb = prev + (size_t)b * CHID * HWPIX + gyc * WW + gxc;
            u32* dst = (u32*)&s1[pc * SP];
            #pragma unroll
            for (int g = 0; g < 6; g++) {
                const float* src = (g < 2) ? (xb + g * 8 * HWPIX)
                                           : (pb + (g * 8 - 16) * HWPIX);
                u32x4 w4;
                #pragma unroll
                for (int h = 0; h < 4; h++) {
                    float v0 = src[(2 * h)     * HWPIX] * mv;
                    float v1 = src[(2 * h + 1) * HWPIX] * mv;
                    w4[h] = (u32)f2b(v0) | ((u32)f2b(v1) << 16);
                }
                *(u32x4*)(dst + g * 4) = w4;
            }
        }
    }
    __syncthreads();

    // ---- shared K-offset table (bytes), same for all three convs ----
    int koff[NKS];
    #pragma unroll
    for (int ks = 0; ks < NKS; ks++) {
        int klin = ks * 4 + run;                 // k = 8*klin
        int tap = imin((klin * 43) >> 8, 8);     // klin/6, clamped to pad
        int ci  = imin((klin - tap * 6) * 8, 40);
        int ky = (tap * 11) >> 5, kx = tap - ky * 3;
        koff[ks] = (((ky * 20 + kx) * SP) + ci) * 2;
    }

    const char* s1c = (const char*)s1;
    const short8* pB8 = (const short8*)pB;
    const f32x4 z4 = {0.f, 0.f, 0.f, 0.f};
    const int baseU = ((1 + w) * 20 + 1 + lo) * SP * 2;   // bytes

    // ========== Phase U: update conv at 16x16 centers (original prev) ==========
    f32x4 accU[4][2];
    #pragma unroll
    for (int f = 0; f < 4; f++) { accU[f][0] = z4; accU[f][1] = z4; }
    {
        short8 bp[2][2];
        bp[0][0] = pB8[(1 * NKS + 0) * 128 + lane];
        bp[0][1] = pB8[(1 * NKS + 0) * 128 + 64 + lane];
        bp[1][0] = pB8[(1 * NKS + 1) * 128 + lane];
        bp[1][1] = pB8[(1 * NKS + 1) * 128 + 64 + lane];
        #pragma unroll
        for (int ks = 0; ks < NKS; ks++) {
            short8 b0 = bp[ks & 1][0], b1 = bp[ks & 1][1];
            if (ks + 2 < NKS) {
                bp[ks & 1][0] = pB8[(1 * NKS + ks + 2) * 128 + lane];
                bp[ks & 1][1] = pB8[(1 * NKS + ks + 2) * 128 + 64 + lane];
            }
            const char* ap = s1c + baseU + koff[ks];
            #pragma unroll
            for (int f = 0; f < 4; f++) {
                short8 av = *(const short8*)(ap + f * (4 * 20 * SP * 2));
                bf16x8 a = __builtin_bit_cast(bf16x8, av);
                accU[f][0] = __builtin_amdgcn_mfma_f32_16x16x32_bf16(a, __builtin_bit_cast(bf16x8, b0), accU[f][0], 0, 0, 0);
                accU[f][1] = __builtin_amdgcn_mfma_f32_16x16x32_bf16(a, __builtin_bit_cast(bf16x8, b1), accU[f][1], 0, 0, 0);
            }
        }
    }

    // ========== Phase R: reset conv on 18x18 halo grid (original prev) ==========
    f32x4 accR[6][2];
    #pragma unroll
    for (int f = 0; f < 6; f++) { accR[f][0] = z4; accR[f][1] = z4; }

    int pbase[6];
    #pragma unroll
    for (int f = 0; f < 6; f++) {
        int frag = w + f * 4;
        int idx = imin(frag * 16 + lo, 323);
        int ry = (idx * 57) >> 10;           // /18
        int rx = idx - ry * 18;
        pbase[f] = (ry * 20 + rx) * SP * 2;  // bytes
    }
    {
        short8 bp[2][2];
        bp[0][0] = pB8[(0 * NKS + 0) * 128 + lane];
        bp[0][1] = pB8[(0 * NKS + 0) * 128 + 64 + lane];
        bp[1][0] = pB8[(0 * NKS + 1) * 128 + lane];
        bp[1][1] = pB8[(0 * NKS + 1) * 128 + 64 + lane];
        #pragma unroll
        for (int ks = 0; ks < NKS; ks++) {
            short8 b0 = bp[ks & 1][0], b1 = bp[ks & 1][1];
            if (ks + 2 < NKS) {
                bp[ks & 1][0] = pB8[(0 * NKS + ks + 2) * 128 + lane];
                bp[ks & 1][1] = pB8[(0 * NKS + ks + 2) * 128 + 64 + lane];
            }
            #pragma unroll
            for (int f = 0; f < 6; f++) {
                if (f == 5 && w > 0) continue;   // frags 0..20 only
                short8 av = *(const short8*)(s1c + pbase[f] + koff[ks]);
                bf16x8 a = __builtin_bit_cast(bf16x8, av);
                accR[f][0] = __builtin_amdgcn_mfma_f32_16x16x32_bf16(a, __builtin_bit_cast(bf16x8, b0), accR[f][0], 0, 0, 0);
                accR[f][1] = __builtin_amdgcn_mfma_f32_16x16x32_bf16(a, __builtin_bit_cast(bf16x8, b1), accR[f][1], 0, 0, 0);
            }
        }
    }

    // ---- pm-save: each thread keeps its epilogue prev*m values (packed) ----
    unsigned pms[4][4];
    #pragma unroll
    for (int f = 0; f < 4; f++) {
        int py = w + f * 4;
        #pragma unroll
        for (int reg = 0; reg < 4; reg++) {
            int px = run * 4 + reg;
            int base = ((py + 2) * 20 + px + 2) * SP + CIN + lo;
            unsigned a0 = s1[base];
            unsigned a1 = s1[base + 16];
            pms[f][reg] = a0 | (a1 << 16);
        }
    }
    __syncthreads();   // all original-prev reads complete before overwrite

    // ---- R epilogue: s1 prev channels <- staged_prev * sigmoid(accR + bR) ----
    {
        float bRv0 = bR[lo], bRv1 = bR[16 + lo];
        #pragma unroll
        for (int f = 0; f < 6; f++) {
            if (f == 5 && w > 0) continue;
            int frag = w + f * 4;
            #pragma unroll
            for (int nf = 0; nf < 2; nf++) {
                int c = nf * 16 + lo;
                float bb = nf ? bRv1 : bRv0;
                #pragma unroll
                for (int reg = 0; reg < 4; reg++) {
                    int idx = frag * 16 + run * 4 + reg;   // m = run*4+reg
                    bool valid = idx < 324;
                    int idc = imin(idx, 323);
                    int ry = (idc * 57) >> 10, rx = idc - ry * 18;
                    int addr = ((ry + 1) * 20 + rx + 1) * SP + CIN + c;
                    float z = accR[f][nf][reg] + bb;
                    z = fminf(fmaxf(z, -30.f), 30.f);
                    float sg = 1.f / (1.f + __expf(-z));
                    float pm = b2f(s1[addr]);
                    if (valid) s1[addr] = f2b(pm * sg);
                }
            }
        }
    }
    __syncthreads();   // overwrite visible before O-phase

    // ========== Phase O: out conv over [x, prev*reset] — same addressing as U ==========
    f32x4 accO[4][2];
    #pragma unroll
    for (int f = 0; f < 4; f++) { accO[f][0] = z4; accO[f][1] = z4; }
    {
        short8 bp[2][2];
        bp[0][0] = pB8[(2 * NKS + 0) * 128 + lane];
        bp[0][1] = pB8[(2 * NKS + 0) * 128 + 64 + lane];
        bp[1][0] = pB8[(2 * NKS + 1) * 128 + lane];
        bp[1][1] = pB8[(2 * NKS + 1) * 128 + 64 + lane];
        #pragma unroll
        for (int ks = 0; ks < NKS; ks++) {
            short8 b0 = bp[ks & 1][0], b1 = bp[ks & 1][1];
            if (ks + 2 < NKS) {
                bp[ks & 1][0] = pB8[(2 * NKS + ks + 2) * 128 + lane];
                bp[ks & 1][1] = pB8[(2 * NKS + ks + 2) * 128 + 64 + lane];
            }
            const char* ap = s1c + baseU + koff[ks];
            #pragma unroll
            for (int f = 0; f < 4; f++) {
                short8 av = *(const short8*)(ap + f * (4 * 20 * SP * 2));
                bf16x8 a = __builtin_bit_cast(bf16x8, av);
                accO[f][0] = __builtin_amdgcn_mfma_f32_16x16x32_bf16(a, __builtin_bit_cast(bf16x8, b0), accO[f][0], 0, 0, 0);
                accO[f][1] = __builtin_amdgcn_mfma_f32_16x16x32_bf16(a, __builtin_bit_cast(bf16x8, b1), accO[f][1], 0, 0, 0);
            }
        }
    }
    __syncthreads();   // O-phase LDS reads done; s1 memory now reusable as sEp

    // ========== Final epilogue: GRU combine -> sEp (LDS transpose) ==========
    {
        float bUv0 = bU[lo], bUv1 = bU[16 + lo];
        float bOv0 = bO[lo], bOv1 = bO[16 + lo];
        #pragma unroll
        for (int f = 0; f < 4; f++) {
            int py = w + f * 4;
            #pragma unroll
            for (int nf = 0; nf < 2; nf++) {
                int c = nf * 16 + lo;
                float bu = nf ? bUv1 : bUv0;
                float bo = nf ? bOv1 : bOv0;
                #pragma unroll
                for (int reg = 0; reg < 4; reg++) {
                    int px = run * 4 + reg;                 // m = run*4+reg
                    float mm = smask[(py + 2) * 20 + px + 2];
                    float zu = accU[f][nf][reg] + bu;
                    zu = fminf(fmaxf(zu, -30.f), 30.f);
                    float uu = mm / (1.f + __expf(-zu));
                    float zo = accO[f][nf][reg] + bo;
                    zo = fminf(fmaxf(zo, -20.f), 20.f);
                    float e2 = __expf(2.f * zo);
                    float t = (1.f - 2.f / (e2 + 1.f)) * mm;   // tanh*m
                    float pm = b2f((u16)((pms[f][reg] >> (nf * 16)) & 0xffffu));
                    sEp[c * 260 + py * 16 + px] = pm * (1.f - uu) + t * uu;
                }
            }
        }
    }
    __syncthreads();

    // ---- coalesced float4 stores ----
    #pragma unroll
    for (int r = 0; r < 8; r++) {
        int i = r * 256 + tid;          // 2048 float4 items
        int c = i >> 6;
        int q = (i & 63) * 4;           // pixel index *4: py = q>>4, px = q&15
        f32x4 v = *(const f32x4*)&sEp[c * 260 + q];
        int py = q >> 4, px = q & 15;
        *(f32x4*)&out[((size_t)(b * CHID + c) * HH + y0 + py) * WW + x0 + px] = v;
    }
}

extern "C" void kernel_launch(void* const* d_in, const int* in_sizes, int n_in,
                              void* d_out, int out_size, void* d_ws, size_t ws_size,
                              hipStream_t stream) {
    const float* x       = (const float*)d_in[0];
    const float* prev    = (const float*)d_in[1];
    const int*   mask    = (const int*)d_in[2];
    const float* w_reset = (const float*)d_in[3];
    const float* b_reset = (const float*)d_in[4];
    const float* w_upd   = (const float*)d_in[5];
    const float* b_upd   = (const float*)d_in[6];
    const float* w_out   = (const float*)d_in[7];
    const float* b_out   = (const float*)d_in[8];
    float* out = (float*)d_out;

    u16* pB = (u16*)d_ws;                        // 3*14*2*64*8 = 43008 bf16 = 86 KB
    const int TOT = 3 * NKS * 2 * 64 * 8;
    packb_kernel<<<(TOT + 255) / 256, 256, 0, stream>>>(w_reset, w_upd, w_out, pB);

    dim3 grid(WW / TS, HH / TS, 8);
    convgru_mfma<<<grid, 256, 0, stream>>>(x, prev, mask, pB,
                                           b_reset, b_upd, b_out, out);
}